// Round 10
// baseline (274.437 us; speedup 1.0000x reference)
//
#include <hip/hip_runtime.h>
#include <math.h>

typedef int intx4 __attribute__((ext_vector_type(4)));
typedef int intx8 __attribute__((ext_vector_type(8)));
typedef float floatx16 __attribute__((ext_vector_type(16)));

#define N_ROWS 8192
#define KDIM 1024

// E8M0 scale bytes: 123 -> 2^-4 per side (data pre-scaled by 2^4 each side)
#define SCALE_WORD 0x7B7B7B7B

// order-preserving float->int encoding for atomicMax
__device__ __forceinline__ int fenc(float f) {
  int i = __float_as_int(f);
  return i >= 0 ? i : (i ^ 0x7fffffff);
}
__device__ __forceinline__ float fdec(int e) {
  int b = e >= 0 ? e : (e ^ 0x7fffffff);
  return __int_as_float(b);
}

// async 16B global->LDS DMA (m97 pattern: per-lane global src, LDS dest must
// equal wave-uniform base + lane*16 -- ours does by construction).
__device__ __forceinline__ void gld_lds16(const void* g, void* l) {
  __builtin_amdgcn_global_load_lds(
      (const __attribute__((address_space(1))) unsigned int*)g,
      (__attribute__((address_space(3))) unsigned int*)l, 16, 0, 0);
}

// One WAVE per row (4 rows/block, no __syncthreads): computes 1/||x|| (fp32),
// writes row normalized*16 as e4m3 via HW cvt, inits the max slot.
__global__ __launch_bounds__(256) void normalize_kernel(
    const float* __restrict__ ex, const float* __restrict__ ey,
    unsigned char* __restrict__ exn, unsigned char* __restrict__ eyn,
    int* __restrict__ rowmax, int* __restrict__ colmax) {
  const int wave = threadIdx.x >> 6, lane = threadIdx.x & 63;
  const int gr = blockIdx.x * 4 + wave;  // 0..16383
  const float* x;
  unsigned char* out;
  int* mslot;
  int row;
  if (gr < N_ROWS) {
    x = ex; out = exn; mslot = rowmax; row = gr;
  } else {
    x = ey; out = eyn; mslot = colmax; row = gr - N_ROWS;
  }
  const float4* xr = (const float4*)(x + (size_t)row * KDIM);
  float4 v[4];
  float ss = 0.f;
#pragma unroll
  for (int j = 0; j < 4; ++j) {
    v[j] = xr[lane + j * 64];  // coalesced
    ss += v[j].x * v[j].x + v[j].y * v[j].y + v[j].z * v[j].z + v[j].w * v[j].w;
  }
#pragma unroll
  for (int off = 32; off > 0; off >>= 1) ss += __shfl_xor(ss, off, 64);
  const float rs = 16.0f * rsqrtf(fmaxf(ss, 1e-24f));  // 2^4 pre-scale
  int* op = (int*)(out + (size_t)row * KDIM);
#pragma unroll
  for (int j = 0; j < 4; ++j) {
    int w = __builtin_amdgcn_cvt_pk_fp8_f32(v[j].x * rs, v[j].y * rs, 0, false);
    w = __builtin_amdgcn_cvt_pk_fp8_f32(v[j].z * rs, v[j].w * rs, w, true);
    op[lane + j * 64] = w;
  }
  if (lane == 0) mslot[row] = (int)0x80000000;  // encoded -inf floor
}

// 256x256 tile GEMM (A @ B^T, row-major K-contiguous e4m3) using MX-scaled
// mfma_scale_f32_32x32x64_f8f6f4, fused with row/col max reduction.
//
// Round-21 change: 16-wave geometry. r19/r20 post-mortem: (512,1) produced
// a BIT-IDENTICAL binary (VGPR 128, WRITE 153.6 MB) -- because the per-SIMD
// register pool is 512/wave-slot (m69: waves/SIMD halves at 64/128/256):
// an 8-wave block = 2 waves/SIMD = HARD 256-reg cap regardless of launch
// bounds. acc[4][2]=128 + ~145 arch > 256 -> the spill was structural.
// Fix: per-wave register shape must fit its occupancy cap. r11's shape
// (acc[2][2]=64 + ~64 arch = 128) is measured-fitting (r11/r15 VGPR 60-64
// WITH 16 staging regs we no longer carry). At 16 waves/block, 1 block/CU
// (96 KB LDS), 4 waves/SIMD -> cap exactly 128. 256^2 tile keeps the
// LDS/FLOP advantage (19.5 vs 23.2 KB/MFLOP at 128^2) and restores the
// 4-waves/SIMD TLP regime that drove r11's implicit overlap.
//  - 1024 thr = 4x4 waves (wm=wave>>2, wn=wave&3), per-wave 64x64 output.
//  - Staging: 1024 lanes x 1 DMA = full 16 KB tile; 2 DMAs/thread/K-tile.
//  - 3-buffer rotation; counted vmcnt(2); ONE barrier per K-tile:
//      {4 RD8 reads(buf t); STAGE t+2 -> buf (t+2)%3} lgkm0; 4 MFMA;
//      WAITV(2); s_barrier
//    Race audit: a wave passes lgkmcnt(0) before its MFMAs, hence before
//    the tail bar => its buf-t reads are COMPLETE at the bar => stage into
//    buf t at tile t+1 is safe. Buf-(t+1) DMA visibility = own WAITV(2)
//    (in-order retirement) + bar. No in-loop drain; t14 tail drains t15.
// Data-path bytes identical (same swizzle store/recover) -> absmax 0.0.
// Tripwires: WRITE_SIZE ~20 MB (spill gone), VGPR ~64-100 not pinned.
//
// LDS swizzle (verified r8): 64-B rows, 16-B chunk c of row r at slot
// c ^ ((r>>1)&3); staging pre-swizzles the per-lane global source chunk so
// the linear lane*16 dest lands swizzle-stored; fragment reads recover
// true chunk 2h+j -> operand bytes at (half,j,b) equal global
// k = k0+(2h+j)*16+b for BOTH A and B -> exact dot-product pairing.
// (Dest row = tid>>2 covers 0..255 at 1024 thr; f(row) = (tid>>3)&3;
// all read-subtile row bases are multiples of 32 -> fsw invariant.)
__global__ __launch_bounds__(1024, 1) void gemm_max_kernel(
    const unsigned char* __restrict__ A, const unsigned char* __restrict__ B,
    int* __restrict__ rowmax, int* __restrict__ colmax) {
  constexpr int TM = 256, BK = 64, K = KDIM;
  constexpr int BUF = TM * BK;                          // 16 KB per buffer
  __shared__ __align__(16) unsigned char sA[3 * BUF];   // 48 KB
  __shared__ __align__(16) unsigned char sB[3 * BUF];   // 48 KB

  const int bm = blockIdx.x, bn = blockIdx.y;
  const int tid = threadIdx.x;  // 0..1023
  const int lane = tid & 63, wave = tid >> 6;
  const int wm = wave >> 2, wn = wave & 3;  // 4x4 waves of 64x64
  const int l32 = lane & 31, half = lane >> 5;
  const int fsw = (l32 >> 1) & 3;                 // f(row) = (row>>1)&3
  const int oLo = (((2 * half + 0) ^ fsw) << 4);  // swizzled slot offsets
  const int oHi = (((2 * half + 1) ^ fsw) << 4);

  const char* Ab = (const char*)(A + (size_t)bm * TM * K);
  const char* Bb = (const char*)(B + (size_t)bn * TM * K);

  floatx16 acc[2][2] = {};

  // Staging: 1024 lanes stage a 256x64 tile (16 KB) per array in ONE DMA.
  // Dest tid*16 -> row tid>>2 (0..255), slot tid&3.
  // Source chunk = (tid&3) ^ f(row) = (tid&3) ^ ((tid>>3)&3).
  const int src_c16 = (((tid & 3) ^ ((tid >> 3) & 3)) << 4);
  const char* gA = Ab + (size_t)(tid >> 2) * K + src_c16;
  const char* gB = Bb + (size_t)(tid >> 2) * K + src_c16;
  unsigned char* wA = sA + tid * 16;  // linear per-lane dest
  unsigned char* wB = sB + tid * 16;

#define STA(k0, buf) gld_lds16(gA + (size_t)(k0), wA + (buf)*BUF)
#define STB(k0, buf) gld_lds16(gB + (size_t)(k0), wB + (buf)*BUF)

#define WAITV(N)                                          \
  do {                                                    \
    asm volatile("s_waitcnt vmcnt(" #N ")" ::: "memory"); \
    __builtin_amdgcn_sched_barrier(0);                    \
  } while (0)

  // swizzle-recovering 16B-pair fragment read (byte math identical to r15)
#define RD8(p)                                                        \
  ({                                                                  \
    const intx4 lo_ = *(const intx4*)((p) + oLo);                     \
    const intx4 hi_ = *(const intx4*)((p) + oHi);                     \
    __builtin_shufflevector(lo_, hi_, 0, 1, 2, 3, 4, 5, 6, 7);        \
  })

#define MFMA(d, a, b)                                                 \
  d = __builtin_amdgcn_mfma_scale_f32_32x32x64_f8f6f4(                \
      (a), (b), (d), 0, 0, 0, SCALE_WORD, 0, SCALE_WORD)

  // One K-tile: {reads || stage t+2} -> lgkm0 -> 4 MFMA -> tail.
  // TAILN: 2 steady (retire tile t+1's 2 DMAs), 0 drain (t14), -1 none.
#define TILE(bufr, bufw, DO_STAGE, k2, TAILN)                               \
  do {                                                                      \
    const unsigned char* aT = &sA[(bufr)*BUF];                              \
    const unsigned char* bT = &sB[(bufr)*BUF];                              \
    const intx8 aF0 = RD8(aT + (wm * 64 + 0 * 32 + l32) * BK);              \
    const intx8 aF1 = RD8(aT + (wm * 64 + 1 * 32 + l32) * BK);              \
    const intx8 bF0 = RD8(bT + (wn * 64 + 0 * 32 + l32) * BK);              \
    const intx8 bF1 = RD8(bT + (wn * 64 + 1 * 32 + l32) * BK);              \
    if (DO_STAGE) {                                                         \
      STA(k2, bufw);                                                        \
      STB(k2, bufw);                                                        \
    }                                                                       \
    asm volatile("s_waitcnt lgkmcnt(0)" ::: "memory");                      \
    __builtin_amdgcn_sched_barrier(0);                                      \
    __builtin_amdgcn_s_setprio(1);                                          \
    MFMA(acc[0][0], aF0, bF0);                                              \
    MFMA(acc[0][1], aF0, bF1);                                              \
    MFMA(acc[1][0], aF1, bF0);                                              \
    MFMA(acc[1][1], aF1, bF1);                                              \
    __builtin_amdgcn_s_setprio(0);                                          \
    if ((TAILN) == 2) {                                                     \
      WAITV(2);                                                             \
      __builtin_amdgcn_s_barrier();                                         \
    } else if ((TAILN) == 0) {                                              \
      WAITV(0);                                                             \
      __builtin_amdgcn_s_barrier();                                         \
    }                                                                       \
  } while (0)

  // Prologue: tiles 0,1 in flight (4 DMAs/lane); retire tile 0's, join.
  STA(0, 0);
  STB(0, 0);
  STA(BK, 1);
  STB(BK, 1);
  WAITV(2);
  __builtin_amdgcn_s_barrier();

  // Steady state: buffers rotate 0,1,2; tile t stages t+2 into (t+2)%3.
#pragma unroll 1
  for (int tt = 0; tt < 12; tt += 3) {
    TILE(0, 2, 1, (size_t)(tt + 2) * BK, 2);
    TILE(1, 0, 1, (size_t)(tt + 3) * BK, 2);
    TILE(2, 1, 1, (size_t)(tt + 4) * BK, 2);
  }
  TILE(0, 2, 1, (size_t)14 * BK, 2);  // tile 12, stages 14
  TILE(1, 0, 1, (size_t)15 * BK, 2);  // tile 13, stages 15
  TILE(2, 0, 0, 0, 0);                // tile 14, drain tile 15's DMAs
  TILE(0, 0, 0, 0, -1);               // tile 15

#undef TILE
#undef STA
#undef STB
#undef RD8
#undef MFMA
#undef WAITV

  // 32x32 C/D layout (m74/m101, dtype-independent):
  //   col = lane&31, row = (reg&3) + 8*(reg>>2) + 4*(lane>>5), reg in [0,16)
  // Row maxes: in-lane over ni, shuffle across 32 cols (masks 1..16 stay
  // within a half), l32==0 lanes write.
#pragma unroll
  for (int mi = 0; mi < 2; ++mi) {
#pragma unroll
    for (int reg = 0; reg < 16; ++reg) {
      float v = fmaxf(acc[mi][0][reg], acc[mi][1][reg]);
#pragma unroll
      for (int m = 1; m < 32; m <<= 1) v = fmaxf(v, __shfl_xor(v, m, 64));
      if (l32 == 0) {
        const int grow = bm * TM + wm * 64 + mi * 32 +
                         (reg & 3) + 8 * (reg >> 2) + 4 * half;
        atomicMax(&rowmax[grow], fenc(v));
      }
    }
  }
  // Col maxes: in-lane over mi,reg (32 vals), combine halves via xor 32.
#pragma unroll
  for (int ni = 0; ni < 2; ++ni) {
    float v = -3.402823466e38f;
#pragma unroll
    for (int mi = 0; mi < 2; ++mi)
#pragma unroll
      for (int reg = 0; reg < 16; ++reg) v = fmaxf(v, acc[mi][ni][reg]);
    v = fmaxf(v, __shfl_xor(v, 32, 64));
    if (half == 0) {
      const int gcol = bn * TM + wn * 64 + ni * 32 + l32;
      atomicMax(&colmax[gcol], fenc(v));
    }
  }
}

__global__ __launch_bounds__(1024) void finalize_kernel(
    const int* __restrict__ rowmax, const int* __restrict__ colmax,
    float* __restrict__ out) {
  const int tid = threadIdx.x;
  float s1 = 0.f, s2 = 0.f;
  for (int i = tid; i < N_ROWS; i += 1024) {
    s1 += 1.0f - fdec(rowmax[i]);
    s2 += 1.0f - fdec(colmax[i]);
  }
#pragma unroll
  for (int off = 32; off > 0; off >>= 1) {
    s1 += __shfl_down(s1, off, 64);
    s2 += __shfl_down(s2, off, 64);
  }
  __shared__ float r1[16], r2[16];
  if ((tid & 63) == 0) {
    r1[tid >> 6] = s1;
    r2[tid >> 6] = s2;
  }
  __syncthreads();
  if (tid == 0) {
    const double SIGMA = 0.3;
    const double H_CONST = 0.5 * log(2.0 * 3.14159265358979323846 * SIGMA * SIGMA) + 0.5;
    const float HS = (float)(H_CONST / SIGMA);
    float a1 = 0.f, a2 = 0.f;
#pragma unroll
    for (int w = 0; w < 16; ++w) {
      a1 += r1[w];
      a2 += r2[w];
    }
    out[0] = HS * a1;
    out[1] = HS * a2;
  }
}

extern "C" void kernel_launch(void* const* d_in, const int* in_sizes, int n_in,
                              void* d_out, int out_size, void* d_ws, size_t ws_size,
                              hipStream_t stream) {
  const float* ex = (const float*)d_in[0];
  const float* ey = (const float*)d_in[1];
  float* out = (float*)d_out;
  char* ws = (char*)d_ws;

  unsigned char* exn = (unsigned char*)ws;                                   // 8 MB
  unsigned char* eyn = (unsigned char*)(ws + (size_t)N_ROWS * KDIM);         // 8 MB
  int* rowmax = (int*)(ws + (size_t)N_ROWS * KDIM * 2);                      // 32 KB
  int* colmax = rowmax + N_ROWS;                                             // 32 KB

  normalize_kernel<<<2 * N_ROWS / 4, 256, 0, stream>>>(ex, ey, exn, eyn, rowmax, colmax);
  gemm_max_kernel<<<dim3(32, 32), 1024, 0, stream>>>(exn, eyn, rowmax, colmax);
  finalize_kernel<<<1, 1024, 0, stream>>>(rowmax, colmax, out);
}

// Round 11
// 194.837 us; speedup vs baseline: 1.4085x; 1.4085x over previous
//
#include <hip/hip_runtime.h>
#include <math.h>

typedef int intx4 __attribute__((ext_vector_type(4)));
typedef int intx8 __attribute__((ext_vector_type(8)));
typedef float floatx16 __attribute__((ext_vector_type(16)));

#define N_ROWS 8192
#define KDIM 1024

// E8M0 scale bytes: 123 -> 2^-4 per side (data pre-scaled by 2^4 each side)
#define SCALE_WORD 0x7B7B7B7B

// order-preserving float->int encoding for atomicMax
__device__ __forceinline__ int fenc(float f) {
  int i = __float_as_int(f);
  return i >= 0 ? i : (i ^ 0x7fffffff);
}
__device__ __forceinline__ float fdec(int e) {
  int b = e >= 0 ? e : (e ^ 0x7fffffff);
  return __int_as_float(b);
}

// async 16B global->LDS DMA (m97 pattern: per-lane global src, LDS dest must
// equal wave-uniform base + lane*16 -- ours does by construction).
__device__ __forceinline__ void gld_lds16(const void* g, void* l) {
  __builtin_amdgcn_global_load_lds(
      (const __attribute__((address_space(1))) unsigned int*)g,
      (__attribute__((address_space(3))) unsigned int*)l, 16, 0, 0);
}

// One WAVE per row (4 rows/block, no __syncthreads): computes 1/||x|| (fp32),
// writes row normalized*16 as e4m3 via HW cvt, inits the max slot.
__global__ __launch_bounds__(256) void normalize_kernel(
    const float* __restrict__ ex, const float* __restrict__ ey,
    unsigned char* __restrict__ exn, unsigned char* __restrict__ eyn,
    int* __restrict__ rowmax, int* __restrict__ colmax) {
  const int wave = threadIdx.x >> 6, lane = threadIdx.x & 63;
  const int gr = blockIdx.x * 4 + wave;  // 0..16383
  const float* x;
  unsigned char* out;
  int* mslot;
  int row;
  if (gr < N_ROWS) {
    x = ex; out = exn; mslot = rowmax; row = gr;
  } else {
    x = ey; out = eyn; mslot = colmax; row = gr - N_ROWS;
  }
  const float4* xr = (const float4*)(x + (size_t)row * KDIM);
  float4 v[4];
  float ss = 0.f;
#pragma unroll
  for (int j = 0; j < 4; ++j) {
    v[j] = xr[lane + j * 64];  // coalesced
    ss += v[j].x * v[j].x + v[j].y * v[j].y + v[j].z * v[j].z + v[j].w * v[j].w;
  }
#pragma unroll
  for (int off = 32; off > 0; off >>= 1) ss += __shfl_xor(ss, off, 64);
  const float rs = 16.0f * rsqrtf(fmaxf(ss, 1e-24f));  // 2^4 pre-scale
  int* op = (int*)(out + (size_t)row * KDIM);
#pragma unroll
  for (int j = 0; j < 4; ++j) {
    int w = __builtin_amdgcn_cvt_pk_fp8_f32(v[j].x * rs, v[j].y * rs, 0, false);
    w = __builtin_amdgcn_cvt_pk_fp8_f32(v[j].z * rs, v[j].w * rs, w, true);
    op[lane + j * 64] = w;
  }
  if (lane == 0) mslot[row] = (int)0x80000000;  // encoded -inf floor
}

// 256x256 tile GEMM (A @ B^T, row-major K-contiguous e4m3) using MX-scaled
// mfma_scale_f32_32x32x64_f8f6f4, fused with row/col max reduction.
//
// Round-22 change: r15's EXACT structure (2-buffer, __syncthreads,
// compiler-scheduled, bF transient) at the 16-wave 256^2 geometry.
// r21 post-mortem: VGPR_Count reports the ARCH half only (r11 clean =
// 64 arch + 64 acc @128 cap; r19 spilled = 128+128 @256 cap). r21's TILE
// held all 4 fragments live between asm fences (lgkm0 + sched_barrier pin
// them materialized) -> arch demand > 64 -> spill (WRITE 316 MB = 1024blk
// x 1024thr x 16 tiles x ~19 B; FETCH +160 MB spill reads). r15's COMPUTE
// shape (aF[2] persistent, bF TRANSIENT per ni, no asm fences) measured
// 60-64 arch CLEAN with identical fragment math. r17 proved the vmcnt
// drain is not the binding cost -> drop all inline asm; let the compiler
// schedule (it kept r15 tight).
// Geometry thesis under test (finally spill-free): 256^2/16-wave halves
// LDS bytes/FLOP (11.4 vs 22.9 KB/MFLOP at 128^2) -- the binding pipe
// since r11. Per block-K-tile: LDS ~1150 cy ~= MFMA ~1100 cy (balanced);
// floor ~31 us/CU-chain.
//  - 1024 thr = 4x4 waves (wm=wave>>2, wn=wave&3), per-wave 64x64 out,
//    acc[2][2] (64 acc + ~64 arch = 128 cap at 4 waves/SIMD, 1 blk/CU).
//  - Staging: 1 DMA/thread/array covers the 256x64 tile (16 KB); stage
//    t+1 before COMPUTE(t); one __syncthreads per K-tile (r15 schedule).
// Data-path bytes identical (same swizzle store/recover; all read-row
// bases are multiples of 32 -> f(row)=fsw invariant) -> absmax 0.0.
// Tripwires: WRITE ~20 MB (spill gone); if clean but gemm ~119 us, the
// LDS-economy thesis is wrong -> plateau discussion.
//
// LDS swizzle (verified r8): 64-B rows, 16-B chunk c of row r at slot
// c ^ ((r>>1)&3); staging pre-swizzles the per-lane global source chunk so
// the linear lane*16 dest lands swizzle-stored; fragment reads recover
// true chunk 2h+j -> operand bytes at (half,j,b) equal global
// k = k0+(2h+j)*16+b for BOTH A and B -> exact dot-product pairing.
// (Dest row = tid>>2 covers 0..255 at 1024 thr; f(row) = (tid>>3)&3.)
__global__ __launch_bounds__(1024, 1) void gemm_max_kernel(
    const unsigned char* __restrict__ A, const unsigned char* __restrict__ B,
    int* __restrict__ rowmax, int* __restrict__ colmax) {
  constexpr int TM = 256, BK = 64, K = KDIM;
  constexpr int BUF = TM * BK;                          // 16 KB per buffer
  __shared__ __align__(16) unsigned char sA[2 * BUF];   // 32 KB
  __shared__ __align__(16) unsigned char sB[2 * BUF];   // 32 KB

  const int bm = blockIdx.x, bn = blockIdx.y;
  const int tid = threadIdx.x;  // 0..1023
  const int lane = tid & 63, wave = tid >> 6;
  const int wm = wave >> 2, wn = wave & 3;  // 4x4 waves of 64x64
  const int l32 = lane & 31, half = lane >> 5;
  const int fsw = (l32 >> 1) & 3;                 // f(row) = (row>>1)&3
  const int oLo = (((2 * half + 0) ^ fsw) << 4);  // swizzled slot offsets
  const int oHi = (((2 * half + 1) ^ fsw) << 4);

  const char* Ab = (const char*)(A + (size_t)bm * TM * K);
  const char* Bb = (const char*)(B + (size_t)bn * TM * K);

  floatx16 acc[2][2] = {};

  // Staging: 1024 lanes stage a 256x64 tile (16 KB) per array in ONE DMA.
  // Dest tid*16 -> row tid>>2 (0..255), slot tid&3.
  // Source chunk = (tid&3) ^ f(row) = (tid&3) ^ ((tid>>3)&3).
  const int src_c16 = (((tid & 3) ^ ((tid >> 3) & 3)) << 4);
  const char* gA = Ab + (size_t)(tid >> 2) * K + src_c16;
  const char* gB = Bb + (size_t)(tid >> 2) * K + src_c16;
  unsigned char* wA = sA + tid * 16;  // linear per-lane dest
  unsigned char* wB = sB + tid * 16;

#define STAGE(k0, buf)                              \
  do {                                              \
    gld_lds16(gA + (size_t)(k0), wA + (buf)*BUF);   \
    gld_lds16(gB + (size_t)(k0), wB + (buf)*BUF);   \
  } while (0)

#define COMPUTE(cur)                                                        \
  do {                                                                      \
    intx8 aF[2];                                                            \
    _Pragma("unroll") for (int mi = 0; mi < 2; ++mi) {                      \
      const unsigned char* aBase =                                          \
          &sA[(cur)*BUF + (wm * 64 + mi * 32 + l32) * BK];                  \
      const intx4 lo = *(const intx4*)(aBase + oLo);                        \
      const intx4 hi = *(const intx4*)(aBase + oHi);                        \
      aF[mi] = __builtin_shufflevector(lo, hi, 0, 1, 2, 3, 4, 5, 6, 7);     \
    }                                                                       \
    _Pragma("unroll") for (int ni = 0; ni < 2; ++ni) {                      \
      const unsigned char* bBase =                                          \
          &sB[(cur)*BUF + (wn * 64 + ni * 32 + l32) * BK];                  \
      const intx4 lo = *(const intx4*)(bBase + oLo);                        \
      const intx4 hi = *(const intx4*)(bBase + oHi);                        \
      const intx8 bF =                                                      \
          __builtin_shufflevector(lo, hi, 0, 1, 2, 3, 4, 5, 6, 7);          \
      _Pragma("unroll") for (int mi = 0; mi < 2; ++mi)                      \
          acc[mi][ni] = __builtin_amdgcn_mfma_scale_f32_32x32x64_f8f6f4(    \
              aF[mi], bF, acc[mi][ni], 0, 0, 0, SCALE_WORD, 0,              \
              SCALE_WORD);                                                  \
    }                                                                       \
  } while (0)

  // Prologue: DMA buf0; barrier drains vmcnt(0) -> tile 0 resident.
  STAGE(0, 0);
  __syncthreads();

  // Steady state (r15 schedule): DMA for s+1 (other buffer) issues BEFORE
  // COMPUTE(s); its latency hides under the MFMA phase; the single
  // end-of-step barrier (vmcnt drain) makes it resident for next step.
#pragma unroll 1
  for (int step = 0; step < K / BK - 1; ++step) {
    STAGE((size_t)(step + 1) * BK, (step + 1) & 1);
    COMPUTE(step & 1);
    __syncthreads();
  }
  COMPUTE((K / BK - 1) & 1);

#undef STAGE
#undef COMPUTE

  // 32x32 C/D layout (m74/m101, dtype-independent):
  //   col = lane&31, row = (reg&3) + 8*(reg>>2) + 4*(lane>>5), reg in [0,16)
  // Row maxes: in-lane over ni, shuffle across 32 cols (masks 1..16 stay
  // within a half), l32==0 lanes write.
#pragma unroll
  for (int mi = 0; mi < 2; ++mi) {
#pragma unroll
    for (int reg = 0; reg < 16; ++reg) {
      float v = fmaxf(acc[mi][0][reg], acc[mi][1][reg]);
#pragma unroll
      for (int m = 1; m < 32; m <<= 1) v = fmaxf(v, __shfl_xor(v, m, 64));
      if (l32 == 0) {
        const int grow = bm * TM + wm * 64 + mi * 32 +
                         (reg & 3) + 8 * (reg >> 2) + 4 * half;
        atomicMax(&rowmax[grow], fenc(v));
      }
    }
  }
  // Col maxes: in-lane over mi,reg (32 vals), combine halves via xor 32.
#pragma unroll
  for (int ni = 0; ni < 2; ++ni) {
    float v = -3.402823466e38f;
#pragma unroll
    for (int mi = 0; mi < 2; ++mi)
#pragma unroll
      for (int reg = 0; reg < 16; ++reg) v = fmaxf(v, acc[mi][ni][reg]);
    v = fmaxf(v, __shfl_xor(v, 32, 64));
    if (half == 0) {
      const int gcol = bn * TM + wn * 64 + ni * 32 + l32;
      atomicMax(&colmax[gcol], fenc(v));
    }
  }
}

__global__ __launch_bounds__(1024) void finalize_kernel(
    const int* __restrict__ rowmax, const int* __restrict__ colmax,
    float* __restrict__ out) {
  const int tid = threadIdx.x;
  float s1 = 0.f, s2 = 0.f;
  for (int i = tid; i < N_ROWS; i += 1024) {
    s1 += 1.0f - fdec(rowmax[i]);
    s2 += 1.0f - fdec(colmax[i]);
  }
#pragma unroll
  for (int off = 32; off > 0; off >>= 1) {
    s1 += __shfl_down(s1, off, 64);
    s2 += __shfl_down(s2, off, 64);
  }
  __shared__ float r1[16], r2[16];
  if ((tid & 63) == 0) {
    r1[tid >> 6] = s1;
    r2[tid >> 6] = s2;
  }
  __syncthreads();
  if (tid == 0) {
    const double SIGMA = 0.3;
    const double H_CONST = 0.5 * log(2.0 * 3.14159265358979323846 * SIGMA * SIGMA) + 0.5;
    const float HS = (float)(H_CONST / SIGMA);
    float a1 = 0.f, a2 = 0.f;
#pragma unroll
    for (int w = 0; w < 16; ++w) {
      a1 += r1[w];
      a2 += r2[w];
    }
    out[0] = HS * a1;
    out[1] = HS * a2;
  }
}

extern "C" void kernel_launch(void* const* d_in, const int* in_sizes, int n_in,
                              void* d_out, int out_size, void* d_ws, size_t ws_size,
                              hipStream_t stream) {
  const float* ex = (const float*)d_in[0];
  const float* ey = (const float*)d_in[1];
  float* out = (float*)d_out;
  char* ws = (char*)d_ws;

  unsigned char* exn = (unsigned char*)ws;                                   // 8 MB
  unsigned char* eyn = (unsigned char*)(ws + (size_t)N_ROWS * KDIM);         // 8 MB
  int* rowmax = (int*)(ws + (size_t)N_ROWS * KDIM * 2);                      // 32 KB
  int* colmax = rowmax + N_ROWS;                                             // 32 KB

  normalize_kernel<<<2 * N_ROWS / 4, 256, 0, stream>>>(ex, ey, exn, eyn, rowmax, colmax);
  gemm_max_kernel<<<dim3(32, 32), 1024, 0, stream>>>(exn, eyn, rowmax, colmax);
  finalize_kernel<<<1, 1024, 0, stream>>>(rowmax, colmax, out);
}